// Round 6
// baseline (200.764 us; speedup 1.0000x reference)
//
#include <hip/hip_runtime.h>
#include <math.h>

#define PRE_NMS 2000
#define POST_NMS 1000
#define IOU_T 0.7f
#define IMGSZ 800.0f
#define CAP 6144            // level-1 candidates per image (expected ~3600)
#define SORTN 2048          // level-2 refined candidates (expected ~2003)
#define NBINS 1024
#define NWORDS 32           // ceil(PRE_NMS/64)
#define NSLICE 16           // blocks per image for hist/compact
#define MROWS 2048          // padded row dim of transposed mask
#define NTILES 528          // NWORDS*(NWORDS+1)/2 upper-triangle tiles
#define TCAP 104            // staged active tiles (53 KiB LDS); overflow -> global

typedef unsigned long long u64;

__device__ __forceinline__ unsigned key_of(float f) {
    unsigned u = __float_as_uint(f);
    return (u & 0x80000000u) ? ~u : (u | 0x80000000u);
}
__device__ __forceinline__ float inv_key(unsigned k) {
    unsigned u = (k & 0x80000000u) ? (k ^ 0x80000000u) : ~k;
    return __uint_as_float(u);
}

// One-wave suffix-scan + threshold find over 1024 bins (replaces 10-round
// LDS ping-pong with ~20 block barriers). Lane owns 16 consecutive bins
// (4 x b128 LDS reads), in-register suffix, 6-step shfl_down over lane
// totals. Finds T s.t. above+suffix(T) >= PRE_NMS > above+suffix(T+1).
// Bit-identical to the old scan's result. Call from wave 0 only.
__device__ __forceinline__ void wave_suffix_thresh(
    const unsigned* __restrict__ h, int above, int lane, int* out_T) {
  const uint4* h4 = (const uint4*)h;
  uint4 q0 = h4[lane * 4 + 0];
  uint4 q1 = h4[lane * 4 + 1];
  uint4 q2 = h4[lane * 4 + 2];
  uint4 q3 = h4[lane * 4 + 3];
  unsigned v[16] = {q0.x, q0.y, q0.z, q0.w, q1.x, q1.y, q1.z, q1.w,
                    q2.x, q2.y, q2.z, q2.w, q3.x, q3.y, q3.z, q3.w};
  #pragma unroll
  for (int j = 14; j >= 0; --j) v[j] += v[j + 1];
  unsigned tot = v[0];
  unsigned x = tot;
  #pragma unroll
  for (int d = 1; d < 64; d <<= 1) {
    unsigned y = __shfl_down(x, d, 64);
    if (lane + d < 64) x += y;
  }
  unsigned excl = x - tot;               // sum of totals for lanes > lane
  #pragma unroll
  for (int j = 0; j < 16; ++j) {
    int cur = above + (int)(v[j] + excl);
    int nxt = above + (int)(((j < 15) ? v[j + 1] : 0u) + excl);
    if (cur >= PRE_NMS && nxt < PRE_NMS) *out_T = lane * 16 + j;
  }
}

// ---- K1: level-1 histogram (10-bit), float2 loads, per-slice store --------
// Also zeroes cand_cnt/gwf/gh2/gabove (replaces memset; stream-ordered).
__global__ __launch_bounds__(256) void hist_kernel(
    const float* __restrict__ scores, int A, unsigned* __restrict__ ghist,
    int* __restrict__ cand_cnt, unsigned* __restrict__ gwf,
    unsigned* __restrict__ gh2, int* __restrict__ gabove) {
  int b = blockIdx.x, slice = blockIdx.y;
  __shared__ unsigned h[NBINS];
  int tid = threadIdx.x;
  for (int i = tid; i < NBINS; i += 256) h[i] = 0;
  if (slice == 0) {
    if (tid == 0) { cand_cnt[b] = 0; gabove[b] = 0; }
    if (tid < NWORDS) gwf[b * NWORDS + tid] = 0u;
    for (int i = tid; i < NBINS; i += 256) gh2[b * NBINS + i] = 0u;
  }
  __syncthreads();
  int nc = A >> 1;                       // A even -> no tail
  int per = (nc + NSLICE - 1) / NSLICE;
  int lo = slice * per, hi = min(lo + per, nc);
  const float2* sc2 = (const float2*)(scores + (size_t)b * A);
  for (int c = lo + tid; c < hi; c += 256) {
    float2 v = sc2[c];
    atomicAdd(&h[key_of(v.x) >> 22], 1u);
    atomicAdd(&h[key_of(v.y) >> 22], 1u);
  }
  __syncthreads();
  unsigned* gh = ghist + ((size_t)b * NSLICE + slice) * NBINS;
  for (int i = tid; i < NBINS; i += 256) gh[i] = h[i];
}

// ---- K2: T1 via wave-scan; compact; fused 20-bit hist for refine ----------
__global__ __launch_bounds__(256) void compact_kernel(
    const float* __restrict__ scores, int A, const unsigned* __restrict__ ghist,
    u64* __restrict__ cand, int* __restrict__ cand_cnt, int* __restrict__ T1,
    unsigned* __restrict__ gh2, int* __restrict__ gabove) {
  int b = blockIdx.x, slice = blockIdx.y;
  int tid = threadIdx.x;
  int lane = tid & 63, wave = tid >> 6;
  __shared__ __align__(16) unsigned h[NBINS];
  __shared__ int sT;
  for (int i = tid; i < NBINS; i += 256) {
    unsigned s = 0;
    const unsigned* gh = ghist + (size_t)b * NSLICE * NBINS + i;
    #pragma unroll
    for (int s16 = 0; s16 < NSLICE; ++s16) s += gh[s16 * NBINS];
    h[i] = s;
  }
  __syncthreads();
  if (wave == 0) wave_suffix_thresh(h, 0, lane, &sT);
  __syncthreads();
  int T = sT;
  if (slice == 0 && tid == 0) T1[b] = T;   // for refine_select
  int nc = A >> 1;
  int per = (nc + NSLICE - 1) / NSLICE;
  int lo = slice * per, hi = min(lo + per, nc);
  const float2* sc2 = (const float2*)(scores + (size_t)b * A);
  int cnt = 0;
  for (int c = lo + tid; c < hi; c += 256) {
    float2 v = sc2[c];
    cnt += ((int)(key_of(v.x) >> 22) >= T);
    cnt += ((int)(key_of(v.y) >> 22) >= T);
  }
  int pfx = cnt;
  #pragma unroll
  for (int d = 1; d < 64; d <<= 1) {
    int t2 = __shfl_up(pfx, d, 64);
    if (lane >= d) pfx += t2;
  }
  __shared__ int s_wt[4];
  __shared__ int s_base;
  if (lane == 63) s_wt[wave] = pfx;
  __syncthreads();
  if (tid == 0) {
    int tot = s_wt[0] + s_wt[1] + s_wt[2] + s_wt[3];
    int acc = 0;
    #pragma unroll
    for (int w2 = 0; w2 < 4; ++w2) { int t3 = s_wt[w2]; s_wt[w2] = acc; acc += t3; }
    s_base = atomicAdd(&cand_cnt[b], tot);
  }
  __syncthreads();
  int my_off = s_base + s_wt[wave] + (pfx - cnt);
  u64* cb = cand + (size_t)b * CAP;
  int na = 0;   // stored candidates strictly above bin T (for refine)
  for (int c = lo + tid; c < hi; c += 256) {
    float2 v = sc2[c];
    unsigned kk[2] = {key_of(v.x), key_of(v.y)};
    #pragma unroll
    for (int j = 0; j < 2; ++j) {
      unsigned k = kk[j];
      if ((int)(k >> 22) >= T) {
        if (my_off < CAP) {
          cb[my_off] = ((u64)k << 32) | (unsigned)(~(2 * c + j));
          if ((int)(k >> 22) > T) na++;
          else atomicAdd(&gh2[b * NBINS + ((k >> 12) & 1023)], 1u);
        }
        my_off++;
      }
    }
  }
  #pragma unroll
  for (int d = 32; d; d >>= 1) na += __shfl_down(na, d, 64);
  if (lane == 0 && na) atomicAdd(&gabove[b], na);
}

// ---- K3: slim refine: wave-scan on precomputed 20-bit hist + one select ---
__global__ __launch_bounds__(256) void refine_select_kernel(
    const u64* __restrict__ cand, const int* __restrict__ cand_cnt,
    const int* __restrict__ T1, const unsigned* __restrict__ gh2,
    const int* __restrict__ gabove,
    u64* __restrict__ gsel, int* __restrict__ sel_cnt) {
  int b = blockIdx.x, tid = threadIdx.x;
  int lane = tid & 63, wave = tid >> 6;
  __shared__ __align__(16) unsigned h2[NBINS];
  __shared__ int s_sel, s_T2;
  for (int i = tid; i < NBINS; i += 256) h2[i] = gh2[b * NBINS + i];
  if (tid == 0) s_sel = 0;
  __syncthreads();
  if (wave == 0) wave_suffix_thresh(h2, gabove[b], lane, &s_T2);
  __syncthreads();
  unsigned thresh20 = ((unsigned)T1[b] << 10) | (unsigned)s_T2;
  int n = min(cand_cnt[b], CAP);
  const u64* cb = cand + (size_t)b * CAP;
  u64* gs = gsel + (size_t)b * SORTN;
  for (int i = tid; i < n; i += 256) {
    u64 cv = cb[i];
    if ((unsigned)(cv >> 44) >= thresh20) {
      int pos = atomicAdd(&s_sel, 1);
      if (pos < SORTN) gs[pos] = cv;
    }
  }
  __syncthreads();
  if (tid == 0) sel_cnt[b] = min(s_sel, SORTN);
}

// ---- K4: parallel rank-count + fused decode (split-half) ------------------
__global__ __launch_bounds__(256) void rank_decode_kernel(
    const u64* __restrict__ gsel, const int* __restrict__ sel_cnt,
    const float* __restrict__ deltas, const float* __restrict__ anchors, int A,
    float* __restrict__ boxes, float* __restrict__ topk_logit) {
  int b = blockIdx.x, ci = blockIdx.y;   // ci in 0..15, 128 candidates each
  int tid = threadIdx.x;
  __shared__ u64 keys[SORTN];   // 16 KiB
  __shared__ int s_part[256];
  const u64* gs = gsel + (size_t)b * SORTN;
  int n = sel_cnt[b];           // in [2000, 2048]
  for (int i = tid; i < SORTN; i += 256)
    keys[i] = (i < n) ? gs[i] : 0ULL;
  __syncthreads();
  int half = tid >> 7;          // waves 0,1 -> half 0; waves 2,3 -> half 1
  int li = tid & 127;
  int i = ci * 128 + li;
  u64 my = keys[i];
  int rank = 0;
  const ulonglong2* k2 = (const ulonglong2*)(keys + half * (SORTN / 2));
  #pragma unroll 4
  for (int j = 0; j < SORTN / 4; ++j) {
    ulonglong2 kk = k2[j];                 // uniform addr -> LDS broadcast
    rank += (kk.x > my) + (kk.y > my);
  }
  s_part[tid] = rank;
  __syncthreads();
  if (half == 0) {
    rank = s_part[tid] + s_part[tid + 128];
    if (i < n && rank < PRE_NMS) {
      int a = (int)(~(unsigned)my);
      topk_logit[b * PRE_NMS + rank] = inv_key((unsigned)(my >> 32));
      const float CLIP = 4.135166556742356f;  // log(1000/16)
      float4 dl = ((const float4*)deltas)[(size_t)b * A + a];
      float4 an = ((const float4*)anchors)[a];
      float wa = __fsub_rn(an.z, an.x);
      float ha = __fsub_rn(an.w, an.y);
      float cxa = __fadd_rn(an.x, __fmul_rn(0.5f, wa));
      float cya = __fadd_rn(an.y, __fmul_rn(0.5f, ha));
      float dw = fminf(dl.z, CLIP), dh = fminf(dl.w, CLIP);
      float cx = __fadd_rn(__fmul_rn(dl.x, wa), cxa);
      float cy = __fadd_rn(__fmul_rn(dl.y, ha), cya);
      float w2 = __fmul_rn((float)exp((double)dw), wa);
      float h2f = __fmul_rn((float)exp((double)dh), ha);
      float x1 = __fsub_rn(cx, __fmul_rn(0.5f, w2));
      float y1 = __fsub_rn(cy, __fmul_rn(0.5f, h2f));
      float x2 = __fadd_rn(cx, __fmul_rn(0.5f, w2));
      float y2 = __fadd_rn(cy, __fmul_rn(0.5f, h2f));
      x1 = fminf(fmaxf(x1, 0.f), IMGSZ);
      y1 = fminf(fmaxf(y1, 0.f), IMGSZ);
      x2 = fminf(fmaxf(x2, 0.f), IMGSZ);
      y2 = fminf(fmaxf(y2, 0.f), IMGSZ);
      ((float4*)boxes)[(size_t)b * PRE_NMS + rank] = make_float4(x1, y1, x2, y2);
    }
  }
}

// ---- K5: IoU tiles, 4 tiles per 256-thr block (one per wave, no barrier) --
__global__ __launch_bounds__(256) void iou_tile(
    const float* __restrict__ boxes, u64* __restrict__ maskT,
    unsigned* __restrict__ gwf) {
  int b = blockIdx.y;
  int tid = threadIdx.x;
  int lane = tid & 63, wave = tid >> 6;
  int k = blockIdx.x * 4 + wave;      // NTILES = 528 = 132*4, always valid
  int wj = (int)((sqrtf(8.0f * k + 1.0f) - 1.0f) * 0.5f);
  while ((wj + 1) * (wj + 2) / 2 <= k) ++wj;
  while (wj * (wj + 1) / 2 > k) --wj;
  int ti = k - wj * (wj + 1) / 2;
  int i = ti * 64 + lane;
  const float4* bb = (const float4*)boxes + (size_t)b * PRE_NMS;
  __shared__ float4 sbox[4][64];
  int jg = wj * 64 + lane;
  sbox[wave][lane] = bb[min(jg, PRE_NMS - 1)];
  float4 A4 = bb[min(i, PRE_NMS - 1)];
  // same-wave LDS write->read: compiler inserts lgkmcnt wait; no barrier
  float area_a = __fmul_rn(__fsub_rn(A4.z, A4.x), __fsub_rn(A4.w, A4.y));
  u64 m = 0;
  #pragma unroll 8
  for (int jj = 0; jj < 64; ++jj) {
    float4 Bb = sbox[wave][jj];            // uniform address -> broadcast
    float area_b = __fmul_rn(__fsub_rn(Bb.z, Bb.x), __fsub_rn(Bb.w, Bb.y));
    float ltx = fmaxf(A4.x, Bb.x), lty = fmaxf(A4.y, Bb.y);
    float rbx = fminf(A4.z, Bb.z), rby = fminf(A4.w, Bb.w);
    float iw = fmaxf(__fsub_rn(rbx, ltx), 0.f);
    float ih = fmaxf(__fsub_rn(rby, lty), 0.f);
    float inter = __fmul_rn(iw, ih);
    float denom = __fadd_rn(__fsub_rn(__fadd_rn(area_a, area_b), inter), 1e-9f);
    // inter/denom > T  <=>  inter > T*denom  (denom > 0); saves the div chain
    int j = wj * 64 + jj;
    if (j > i && inter > __fmul_rn(IOU_T, denom)) m |= 1ULL << jj;
  }
  u64 anyb = __ballot(m != 0ULL);
  if (anyb) {
    maskT[((size_t)b * NWORDS + wj) * MROWS + i] = m;  // only nonzero tiles
    if (lane == 0) atomicOr(&gwf[b * NWORDS + ti], 1u << wj);
  }
}

// ---- K6: NMS scan v11 — sparse single-wave scan, active windows only ------
__global__ __launch_bounds__(256, 1) void nms_scan(
    const u64* __restrict__ maskT, const unsigned* __restrict__ gwf,
    const float* __restrict__ boxes,
    const float* __restrict__ logits, float* __restrict__ out) {
  int b = blockIdx.x;
  int tid = threadIdx.x;
  int lane = tid & 63, wave = tid >> 6;
  __shared__ u64 tiles[TCAP][64];          // 53 KiB
  __shared__ unsigned swf[NWORDS];
  __shared__ int wbase[NWORDS];
  __shared__ unsigned short slot2cw[TCAP]; // (w2<<8)|c
  __shared__ int s_nact;
  __shared__ u64 s_keep[NWORDS];
  __shared__ int pre[NWORDS];
  __shared__ int s_tot;
  const u64* mb = maskT + (size_t)b * NWORDS * MROWS;
  if (tid < NWORDS) swf[tid] = gwf[b * NWORDS + tid];
  __syncthreads();
  if (tid == 0) {   // serial slot assignment (~#active iterations, all LDS/ALU)
    int s = 0;
    for (int c = 0; c < NWORDS; ++c) {
      wbase[c] = s;
      unsigned wf = swf[c];
      while (wf) {
        int w2 = __ffs(wf) - 1; wf &= wf - 1;
        if (s < TCAP) slot2cw[s] = (unsigned short)((w2 << 8) | c);
        s++;
      }
    }
    s_nact = s;
  }
  __syncthreads();
  // stage active tiles to LDS (coalesced 512B per tile)
  int nstage = min(s_nact, TCAP);
  for (int g = tid; g < nstage * 64; g += 256) {
    int slot = g >> 6, r = g & 63;
    unsigned cw = slot2cw[slot];
    int c = cw & 0xFF, w2 = cw >> 8;
    tiles[slot][r] = mb[(size_t)w2 * MROWS + c * 64 + r];
  }
  __syncthreads();
  // single-wave barrier-free scan over ACTIVE windows only
  if (wave == 0) {
    u64 keep = (lane < NWORDS) ? ((lane == NWORDS - 1) ? 0xFFFFULL : ~0ULL) : 0ULL;
    unsigned wfreg = (lane < NWORDS) ? swf[lane] : 0u;
    int baser = (lane < NWORDS) ? wbase[lane] : 0;
    unsigned wmask = (unsigned)__ballot(wfreg != 0u);   // windows 0..31
    while (wmask) {
      int c = __ffs(wmask) - 1; wmask &= wmask - 1;
      unsigned wf = __shfl(wfreg, c, 64);
      int base = __shfl(baser, c, 64);
      u64 cur = __shfl(keep, c, 64);       // keep[c] broadcast
      if ((wf >> c) & 1u) {                // diag tile active (lowest bit of wf)
        int slot = base;
        u64 d = (slot < TCAP) ? tiles[slot][lane]
                              : mb[(size_t)c * MROWS + c * 64 + lane];
        unsigned dlo = (unsigned)d, dhi = (unsigned)(d >> 32);
        unsigned clo = __builtin_amdgcn_readfirstlane((unsigned)cur);
        unsigned chi = __builtin_amdgcn_readfirstlane((unsigned)(cur >> 32));
        #pragma unroll
        for (int bb = 0; bb < 32; ++bb) {
          unsigned rlo = __builtin_amdgcn_readlane(dlo, bb);
          unsigned rhi = __builtin_amdgcn_readlane(dhi, bb);
          unsigned msk = 0u - ((clo >> bb) & 1u);
          clo &= ~(rlo & msk);
          chi &= ~(rhi & msk);
        }
        #pragma unroll
        for (int bb = 0; bb < 32; ++bb) {
          unsigned rlo = __builtin_amdgcn_readlane(dlo, bb + 32);
          unsigned rhi = __builtin_amdgcn_readlane(dhi, bb + 32);
          unsigned msk = 0u - ((chi >> bb) & 1u);
          clo &= ~(rlo & msk);
          chi &= ~(rhi & msk);
        }
        cur = ((u64)chi << 32) | clo;
        keep = (lane == c) ? cur : keep;
      }
      unsigned rem = wf & ~(1u << c);      // off-diagonal targets (all > c)
      while (rem) {
        int w2 = __ffs(rem) - 1; rem &= rem - 1;
        int slot = base + __popc(wf & ((1u << w2) - 1u));
        u64 row = (slot < TCAP) ? tiles[slot][lane]
                                : mb[(size_t)w2 * MROWS + c * 64 + lane];
        u64 bit = (cur >> lane) & 1ULL;
        u64 v = row & (0ULL - bit);
        u64 mnz = __ballot(v != 0ULL);     // typically 1-3 lanes
        u64 sv = 0;
        while (mnz) {
          int l = (int)__ffsll((long long)mnz) - 1; mnz &= mnz - 1;
          unsigned slo = __builtin_amdgcn_readlane((unsigned)v, l);
          unsigned shi = __builtin_amdgcn_readlane((unsigned)(v >> 32), l);
          sv |= ((u64)shi << 32) | slo;
        }
        keep = (lane == w2) ? (keep & ~sv) : keep;
      }
    }
    if (lane < NWORDS) s_keep[lane] = keep;
  }
  __syncthreads();
  // fused emit: rank kept boxes, write [box, sigmoid]; zero rows >= total
  if (tid == 0) {
    int acc = 0;
    for (int ww = 0; ww < NWORDS; ++ww) {
      pre[ww] = acc;
      acc += __popcll(s_keep[ww]);
    }
    s_tot = acc;
  }
  __syncthreads();
  const float* lg_b = logits + b * PRE_NMS;
  const float4* bx_b = (const float4*)boxes + (size_t)b * PRE_NMS;
  for (int i = tid; i < PRE_NMS; i += 256) {
    u64 wv = s_keep[i >> 6];
    if ((wv >> (i & 63)) & 1) {
      int rank = pre[i >> 6] + __popcll(wv & ((1ULL << (i & 63)) - 1ULL));
      if (rank < POST_NMS) {
        float4 bx = bx_b[i];
        float lg = lg_b[i];
        float e = (float)exp(-(double)lg);
        float pp = 1.0f / (1.0f + e);
        float* o = out + ((size_t)b * POST_NMS + rank) * 5;
        o[0] = bx.x; o[1] = bx.y; o[2] = bx.z; o[3] = bx.w; o[4] = pp;
      }
    }
  }
  int tot = s_tot;
  for (int j = tid; j < POST_NMS; j += 256) {
    if (j >= tot) {
      float* o = out + ((size_t)b * POST_NMS + j) * 5;
      o[0] = 0.f; o[1] = 0.f; o[2] = 0.f; o[3] = 0.f; o[4] = 0.f;
    }
  }
}

extern "C" void kernel_launch(void* const* d_in, const int* in_sizes, int n_in,
                              void* d_out, int out_size, void* d_ws, size_t ws_size,
                              hipStream_t stream) {
  const float* scores  = (const float*)d_in[0];
  const float* deltas  = (const float*)d_in[1];
  const float* anchors = (const float*)d_in[2];
  int A = in_sizes[2] / 4;          // 159882
  int B = in_sizes[0] / A;          // 16

  char* ws = (char*)d_ws;
  size_t off = 0;
  auto alloc = [&](size_t bytes) {
    void* p = ws + off;
    off += (bytes + 255) & ~(size_t)255;
    return p;
  };
  unsigned* ghist    = (unsigned*)alloc((size_t)B * NSLICE * NBINS * 4);
  int*      cand_cnt = (int*)alloc((size_t)B * 4);
  int*      T1       = (int*)alloc((size_t)B * 4);
  u64*      cand     = (u64*)alloc((size_t)B * CAP * 8);
  u64*      gsel     = (u64*)alloc((size_t)B * SORTN * 8);
  int*      sel_cnt  = (int*)alloc((size_t)B * 4);
  float*    topk_lg  = (float*)alloc((size_t)B * PRE_NMS * 4);
  float*    boxes    = (float*)alloc((size_t)B * PRE_NMS * 16);
  u64*      maskT    = (u64*)alloc((size_t)B * NWORDS * MROWS * 8);
  unsigned* gwf      = (unsigned*)alloc((size_t)B * NWORDS * 4);
  unsigned* gh2      = (unsigned*)alloc((size_t)B * NBINS * 4);
  int*      gabove   = (int*)alloc((size_t)B * 4);

  hist_kernel<<<dim3(B, NSLICE), 256, 0, stream>>>(
      scores, A, ghist, cand_cnt, gwf, gh2, gabove);
  compact_kernel<<<dim3(B, NSLICE), 256, 0, stream>>>(
      scores, A, ghist, cand, cand_cnt, T1, gh2, gabove);
  refine_select_kernel<<<B, 256, 0, stream>>>(
      cand, cand_cnt, T1, gh2, gabove, gsel, sel_cnt);
  rank_decode_kernel<<<dim3(B, SORTN / 128), 256, 0, stream>>>(
      gsel, sel_cnt, deltas, anchors, A, boxes, topk_lg);
  iou_tile<<<dim3(NTILES / 4, B), 256, 0, stream>>>(boxes, maskT, gwf);
  nms_scan<<<B, 256, 0, stream>>>(maskT, gwf, boxes, topk_lg, (float*)d_out);
}

// Round 7
// 195.532 us; speedup vs baseline: 1.0268x; 1.0268x over previous
//
#include <hip/hip_runtime.h>
#include <math.h>

#define PRE_NMS 2000
#define POST_NMS 1000
#define IOU_T 0.7f
#define IMGSZ 800.0f
#define CAP 6144            // level-1 candidates per image (expected ~3600)
#define SORTN 2048          // level-2 refined candidates (expected ~2003)
#define NBINS 1024
#define NWORDS 32           // ceil(PRE_NMS/64)
#define NSLICE 16           // blocks per image for hist/compact
#define MROWS 2048          // padded row dim of transposed mask
#define NTILES 528          // NWORDS*(NWORDS+1)/2 upper-triangle tiles
#define TCAP 104            // staged active tiles (53 KiB LDS); overflow -> global

typedef unsigned long long u64;

__device__ __forceinline__ unsigned key_of(float f) {
    unsigned u = __float_as_uint(f);
    return (u & 0x80000000u) ? ~u : (u | 0x80000000u);
}
__device__ __forceinline__ float inv_key(unsigned k) {
    unsigned u = (k & 0x80000000u) ? (k ^ 0x80000000u) : ~k;
    return __uint_as_float(u);
}

// ---- K1: level-1 histogram (10-bit), per-slice non-atomic store ----------
// Also zeroes cand_cnt and gwf (replaces memset dispatch; stream-ordered
// before their consumers).
__global__ __launch_bounds__(256) void hist_kernel(
    const float* __restrict__ scores, int A, unsigned* __restrict__ ghist,
    int* __restrict__ cand_cnt, unsigned* __restrict__ gwf) {
  int b = blockIdx.x, slice = blockIdx.y;
  __shared__ unsigned h[NBINS];
  int tid = threadIdx.x;
  for (int i = tid; i < NBINS; i += 256) h[i] = 0;
  if (slice == 0) {
    if (tid == 0) cand_cnt[b] = 0;
    if (tid < NWORDS) gwf[b * NWORDS + tid] = 0u;
  }
  __syncthreads();
  int per = (A + NSLICE - 1) / NSLICE;
  int lo = slice * per, hi = min(lo + per, A);
  const float* sc = scores + (size_t)b * A;
  for (int i = lo + tid; i < hi; i += 256)
    atomicAdd(&h[key_of(sc[i]) >> 22], 1u);
  __syncthreads();
  unsigned* gh = ghist + ((size_t)b * NSLICE + slice) * NBINS;
  for (int i = tid; i < NBINS; i += 256) gh[i] = h[i];
}

// ---- K2: compact above T1; T1 computed in-block (sums 16 slice hists) ----
__global__ __launch_bounds__(256) void compact_kernel(
    const float* __restrict__ scores, int A, const unsigned* __restrict__ ghist,
    u64* __restrict__ cand, int* __restrict__ cand_cnt, int* __restrict__ T1) {
  int b = blockIdx.x, slice = blockIdx.y;
  int tid = threadIdx.x;
  int lane = tid & 63, wave = tid >> 6;
  __shared__ unsigned sa[2][NBINS];
  __shared__ int sT;
  for (int i = tid; i < NBINS; i += 256) {
    unsigned s = 0;
    const unsigned* gh = ghist + (size_t)b * NSLICE * NBINS + i;
    #pragma unroll
    for (int s16 = 0; s16 < NSLICE; ++s16) s += gh[s16 * NBINS];
    sa[0][i] = s;
  }
  __syncthreads();
  int src = 0;
  for (int d = 1; d < NBINS; d <<= 1) {
    for (int i = tid; i < NBINS; i += 256)
      sa[src ^ 1][i] = sa[src][i] + ((i + d < NBINS) ? sa[src][i + d] : 0u);
    __syncthreads();
    src ^= 1;
  }
  for (int i = tid; i < NBINS; i += 256) {
    unsigned v = sa[src][i];
    unsigned nx = (i < NBINS - 1) ? sa[src][i + 1] : 0u;
    if (v >= PRE_NMS && nx < PRE_NMS) sT = i;
  }
  __syncthreads();
  int T = sT;
  if (slice == 0 && tid == 0) T1[b] = T;   // for refine_select
  int per = (A + NSLICE - 1) / NSLICE;
  int lo = slice * per, hi = min(lo + per, A);
  const float* sc = scores + (size_t)b * A;
  int cnt = 0;
  for (int i = lo + tid; i < hi; i += 256)
    cnt += ((int)(key_of(sc[i]) >> 22) >= T);
  int pfx = cnt;
  #pragma unroll
  for (int d = 1; d < 64; d <<= 1) {
    int t2 = __shfl_up(pfx, d, 64);
    if (lane >= d) pfx += t2;
  }
  __shared__ int s_wt[4];
  __shared__ int s_base;
  if (lane == 63) s_wt[wave] = pfx;
  __syncthreads();
  if (tid == 0) {
    int tot = s_wt[0] + s_wt[1] + s_wt[2] + s_wt[3];
    int acc = 0;
    #pragma unroll
    for (int w2 = 0; w2 < 4; ++w2) { int t3 = s_wt[w2]; s_wt[w2] = acc; acc += t3; }
    s_base = atomicAdd(&cand_cnt[b], tot);
  }
  __syncthreads();
  int my_off = s_base + s_wt[wave] + (pfx - cnt);
  u64* cb = cand + (size_t)b * CAP;
  for (int i = lo + tid; i < hi; i += 256) {
    unsigned k = key_of(sc[i]);
    if ((int)(k >> 22) >= T) {
      if (my_off < CAP) cb[my_off] = ((u64)k << 32) | (unsigned)(~i);
      my_off++;
    }
  }
}

// ---- K3: 20-bit threshold refinement, select ~2000-2048 cands (unsorted) --
__global__ __launch_bounds__(1024) void refine_select_kernel(
    const u64* __restrict__ cand, const int* __restrict__ cand_cnt,
    const int* __restrict__ T1,
    u64* __restrict__ gsel, int* __restrict__ sel_cnt) {
  int b = blockIdx.x, tid = threadIdx.x;
  int lane = tid & 63;
  __shared__ unsigned h2[NBINS];
  __shared__ unsigned tmp[NBINS];
  __shared__ int s_above, s_sel, s_T2;
  int n = min(cand_cnt[b], CAP);
  const u64* cb = cand + (size_t)b * CAP;
  h2[tid] = 0;
  if (tid == 0) { s_above = 0; s_sel = 0; }
  __syncthreads();
  int T1v = T1[b];
  int loc = 0;
  for (int i = tid; i < n; i += 1024) {
    unsigned k = (unsigned)(cb[i] >> 32);
    if ((int)(k >> 22) > T1v) loc++;
    else atomicAdd(&h2[(k >> 12) & 1023], 1u);
  }
  for (int d = 32; d; d >>= 1) loc += __shfl_down(loc, d, 64);
  if (lane == 0 && loc) atomicAdd(&s_above, loc);
  __syncthreads();
  unsigned v = h2[tid];
  for (int d = 1; d < NBINS; d <<= 1) {
    tmp[tid] = v;
    __syncthreads();
    if (tid + d < NBINS) v += tmp[tid + d];
    __syncthreads();
  }
  tmp[tid] = v;
  __syncthreads();
  int above = s_above;
  unsigned nextv = (tid < NBINS - 1) ? tmp[tid + 1] : 0u;
  if (above + (int)v >= PRE_NMS && above + (int)nextv < PRE_NMS) s_T2 = tid;
  __syncthreads();
  unsigned thresh20 = ((unsigned)T1v << 10) | (unsigned)s_T2;
  u64* gs = gsel + (size_t)b * SORTN;
  for (int i = tid; i < n; i += 1024) {
    u64 cv = cb[i];
    if ((unsigned)(cv >> 44) >= thresh20) {
      int pos = atomicAdd(&s_sel, 1);
      if (pos < SORTN) gs[pos] = cv;
    }
  }
  __syncthreads();
  if (tid == 0) sel_cnt[b] = min(s_sel, SORTN);
}

// ---- K4: parallel rank-count + fused decode (split-half) ------------------
__global__ __launch_bounds__(256) void rank_decode_kernel(
    const u64* __restrict__ gsel, const int* __restrict__ sel_cnt,
    const float* __restrict__ deltas, const float* __restrict__ anchors, int A,
    float* __restrict__ boxes, float* __restrict__ topk_logit) {
  int b = blockIdx.x, ci = blockIdx.y;   // ci in 0..15, 128 candidates each
  int tid = threadIdx.x;
  __shared__ u64 keys[SORTN];   // 16 KiB
  __shared__ int s_part[256];
  const u64* gs = gsel + (size_t)b * SORTN;
  int n = sel_cnt[b];           // in [2000, 2048]
  for (int i = tid; i < SORTN; i += 256)
    keys[i] = (i < n) ? gs[i] : 0ULL;
  __syncthreads();
  int half = tid >> 7;          // waves 0,1 -> half 0; waves 2,3 -> half 1
  int li = tid & 127;
  int i = ci * 128 + li;
  u64 my = keys[i];
  int rank = 0;
  const ulonglong2* k2 = (const ulonglong2*)(keys + half * (SORTN / 2));
  #pragma unroll 4
  for (int j = 0; j < SORTN / 4; ++j) {
    ulonglong2 kk = k2[j];                 // uniform addr -> LDS broadcast
    rank += (kk.x > my) + (kk.y > my);
  }
  s_part[tid] = rank;
  __syncthreads();
  if (half == 0) {
    rank = s_part[tid] + s_part[tid + 128];
    if (i < n && rank < PRE_NMS) {
      int a = (int)(~(unsigned)my);
      topk_logit[b * PRE_NMS + rank] = inv_key((unsigned)(my >> 32));
      const float CLIP = 4.135166556742356f;  // log(1000/16)
      float4 dl = ((const float4*)deltas)[(size_t)b * A + a];
      float4 an = ((const float4*)anchors)[a];
      float wa = __fsub_rn(an.z, an.x);
      float ha = __fsub_rn(an.w, an.y);
      float cxa = __fadd_rn(an.x, __fmul_rn(0.5f, wa));
      float cya = __fadd_rn(an.y, __fmul_rn(0.5f, ha));
      float dw = fminf(dl.z, CLIP), dh = fminf(dl.w, CLIP);
      float cx = __fadd_rn(__fmul_rn(dl.x, wa), cxa);
      float cy = __fadd_rn(__fmul_rn(dl.y, ha), cya);
      float w2 = __fmul_rn((float)exp((double)dw), wa);
      float h2f = __fmul_rn((float)exp((double)dh), ha);
      float x1 = __fsub_rn(cx, __fmul_rn(0.5f, w2));
      float y1 = __fsub_rn(cy, __fmul_rn(0.5f, h2f));
      float x2 = __fadd_rn(cx, __fmul_rn(0.5f, w2));
      float y2 = __fadd_rn(cy, __fmul_rn(0.5f, h2f));
      x1 = fminf(fmaxf(x1, 0.f), IMGSZ);
      y1 = fminf(fmaxf(y1, 0.f), IMGSZ);
      x2 = fminf(fmaxf(x2, 0.f), IMGSZ);
      y2 = fminf(fmaxf(y2, 0.f), IMGSZ);
      ((float4*)boxes)[(size_t)b * PRE_NMS + rank] = make_float4(x1, y1, x2, y2);
    }
  }
}

// ---- K5: IoU tiles. Division-free; nonzero tiles -> maskT + gwf bitmap ----
__global__ __launch_bounds__(64) void iou_tile(
    const float* __restrict__ boxes, u64* __restrict__ maskT,
    unsigned* __restrict__ gwf) {
  int k = blockIdx.x;       // 0..527 -> (ti <= wj) pair
  int b = blockIdx.y;
  int wj = (int)((sqrtf(8.0f * k + 1.0f) - 1.0f) * 0.5f);
  while ((wj + 1) * (wj + 2) / 2 <= k) ++wj;
  while (wj * (wj + 1) / 2 > k) --wj;
  int ti = k - wj * (wj + 1) / 2;
  int lane = threadIdx.x;
  int i = ti * 64 + lane;
  const float4* bb = (const float4*)boxes + (size_t)b * PRE_NMS;
  __shared__ float4 sbox[64];
  int jg = wj * 64 + lane;
  sbox[lane] = bb[min(jg, PRE_NMS - 1)];
  float4 A4 = bb[min(i, PRE_NMS - 1)];
  __syncthreads();
  float area_a = __fmul_rn(__fsub_rn(A4.z, A4.x), __fsub_rn(A4.w, A4.y));
  u64 m = 0;
  #pragma unroll 8
  for (int jj = 0; jj < 64; ++jj) {
    float4 Bb = sbox[jj];                  // uniform address -> broadcast
    float area_b = __fmul_rn(__fsub_rn(Bb.z, Bb.x), __fsub_rn(Bb.w, Bb.y));
    float ltx = fmaxf(A4.x, Bb.x), lty = fmaxf(A4.y, Bb.y);
    float rbx = fminf(A4.z, Bb.z), rby = fminf(A4.w, Bb.w);
    float iw = fmaxf(__fsub_rn(rbx, ltx), 0.f);
    float ih = fmaxf(__fsub_rn(rby, lty), 0.f);
    float inter = __fmul_rn(iw, ih);
    float denom = __fadd_rn(__fsub_rn(__fadd_rn(area_a, area_b), inter), 1e-9f);
    // inter/denom > T  <=>  inter > T*denom  (denom > 0); saves the div chain
    int j = wj * 64 + jj;
    if (j > i && inter > __fmul_rn(IOU_T, denom)) m |= 1ULL << jj;
  }
  u64 anyb = __ballot(m != 0ULL);
  if (anyb) {
    maskT[((size_t)b * NWORDS + wj) * MROWS + i] = m;  // only nonzero tiles
    if (lane == 0) atomicOr(&gwf[b * NWORDS + ti], 1u << wj);
  }
}

// ---- K6: NMS scan v11 — sparse single-wave scan, active windows only ------
// wflags come as a 32-word bitmap (gwf) written by iou_tile -> ONE coalesced
// load. Wave 0 keeps wflags, wbase, and keep-words in lane registers;
// iterates ONLY windows whose wflags word is nonzero (skipped windows
// provably cannot change keep). Per-tile OR-reduce = ballot + uniform
// readlane over the (typically 1-3) nonzero lanes.
__global__ __launch_bounds__(256, 1) void nms_scan(
    const u64* __restrict__ maskT, const unsigned* __restrict__ gwf,
    const float* __restrict__ boxes,
    const float* __restrict__ logits, float* __restrict__ out) {
  int b = blockIdx.x;
  int tid = threadIdx.x;
  int lane = tid & 63, wave = tid >> 6;
  __shared__ u64 tiles[TCAP][64];          // 53 KiB
  __shared__ unsigned swf[NWORDS];
  __shared__ int wbase[NWORDS];
  __shared__ unsigned short slot2cw[TCAP]; // (w2<<8)|c
  __shared__ int s_nact;
  __shared__ u64 s_keep[NWORDS];
  __shared__ int pre[NWORDS];
  __shared__ int s_tot;
  const u64* mb = maskT + (size_t)b * NWORDS * MROWS;
  if (tid < NWORDS) swf[tid] = gwf[b * NWORDS + tid];
  __syncthreads();
  if (tid == 0) {   // serial slot assignment (~#active iterations, all LDS/ALU)
    int s = 0;
    for (int c = 0; c < NWORDS; ++c) {
      wbase[c] = s;
      unsigned wf = swf[c];
      while (wf) {
        int w2 = __ffs(wf) - 1; wf &= wf - 1;
        if (s < TCAP) slot2cw[s] = (unsigned short)((w2 << 8) | c);
        s++;
      }
    }
    s_nact = s;
  }
  __syncthreads();
  // stage active tiles to LDS (coalesced 512B per tile)
  int nstage = min(s_nact, TCAP);
  for (int g = tid; g < nstage * 64; g += 256) {
    int slot = g >> 6, r = g & 63;
    unsigned cw = slot2cw[slot];
    int c = cw & 0xFF, w2 = cw >> 8;
    tiles[slot][r] = mb[(size_t)w2 * MROWS + c * 64 + r];
  }
  __syncthreads();
  // single-wave barrier-free scan over ACTIVE windows only
  if (wave == 0) {
    u64 keep = (lane < NWORDS) ? ((lane == NWORDS - 1) ? 0xFFFFULL : ~0ULL) : 0ULL;
    unsigned wfreg = (lane < NWORDS) ? swf[lane] : 0u;
    int baser = (lane < NWORDS) ? wbase[lane] : 0;
    unsigned wmask = (unsigned)__ballot(wfreg != 0u);   // windows 0..31
    while (wmask) {
      int c = __ffs(wmask) - 1; wmask &= wmask - 1;
      unsigned wf = __shfl(wfreg, c, 64);
      int base = __shfl(baser, c, 64);
      u64 cur = __shfl(keep, c, 64);       // keep[c] broadcast
      if ((wf >> c) & 1u) {                // diag tile active (lowest bit of wf)
        int slot = base;
        u64 d = (slot < TCAP) ? tiles[slot][lane]
                              : mb[(size_t)c * MROWS + c * 64 + lane];
        unsigned dlo = (unsigned)d, dhi = (unsigned)(d >> 32);
        unsigned clo = __builtin_amdgcn_readfirstlane((unsigned)cur);
        unsigned chi = __builtin_amdgcn_readfirstlane((unsigned)(cur >> 32));
        #pragma unroll
        for (int bb = 0; bb < 32; ++bb) {
          unsigned rlo = __builtin_amdgcn_readlane(dlo, bb);
          unsigned rhi = __builtin_amdgcn_readlane(dhi, bb);
          unsigned msk = 0u - ((clo >> bb) & 1u);
          clo &= ~(rlo & msk);
          chi &= ~(rhi & msk);
        }
        #pragma unroll
        for (int bb = 0; bb < 32; ++bb) {
          unsigned rlo = __builtin_amdgcn_readlane(dlo, bb + 32);
          unsigned rhi = __builtin_amdgcn_readlane(dhi, bb + 32);
          unsigned msk = 0u - ((chi >> bb) & 1u);
          clo &= ~(rlo & msk);
          chi &= ~(rhi & msk);
        }
        cur = ((u64)chi << 32) | clo;
        keep = (lane == c) ? cur : keep;
      }
      unsigned rem = wf & ~(1u << c);      // off-diagonal targets (all > c)
      while (rem) {
        int w2 = __ffs(rem) - 1; rem &= rem - 1;
        int slot = base + __popc(wf & ((1u << w2) - 1u));
        u64 row = (slot < TCAP) ? tiles[slot][lane]
                                : mb[(size_t)w2 * MROWS + c * 64 + lane];
        u64 bit = (cur >> lane) & 1ULL;
        u64 v = row & (0ULL - bit);
        u64 mnz = __ballot(v != 0ULL);     // typically 1-3 lanes
        u64 sv = 0;
        while (mnz) {
          int l = (int)__ffsll((long long)mnz) - 1; mnz &= mnz - 1;
          unsigned slo = __builtin_amdgcn_readlane((unsigned)v, l);
          unsigned shi = __builtin_amdgcn_readlane((unsigned)(v >> 32), l);
          sv |= ((u64)shi << 32) | slo;
        }
        keep = (lane == w2) ? (keep & ~sv) : keep;
      }
    }
    if (lane < NWORDS) s_keep[lane] = keep;
  }
  __syncthreads();
  // fused emit: rank kept boxes, write [box, sigmoid]; zero rows >= total
  if (tid == 0) {
    int acc = 0;
    for (int ww = 0; ww < NWORDS; ++ww) {
      pre[ww] = acc;
      acc += __popcll(s_keep[ww]);
    }
    s_tot = acc;
  }
  __syncthreads();
  const float* lg_b = logits + b * PRE_NMS;
  const float4* bx_b = (const float4*)boxes + (size_t)b * PRE_NMS;
  for (int i = tid; i < PRE_NMS; i += 256) {
    u64 wv = s_keep[i >> 6];
    if ((wv >> (i & 63)) & 1) {
      int rank = pre[i >> 6] + __popcll(wv & ((1ULL << (i & 63)) - 1ULL));
      if (rank < POST_NMS) {
        float4 bx = bx_b[i];
        float lg = lg_b[i];
        float e = (float)exp(-(double)lg);
        float pp = 1.0f / (1.0f + e);
        float* o = out + ((size_t)b * POST_NMS + rank) * 5;
        o[0] = bx.x; o[1] = bx.y; o[2] = bx.z; o[3] = bx.w; o[4] = pp;
      }
    }
  }
  int tot = s_tot;
  for (int j = tid; j < POST_NMS; j += 256) {
    if (j >= tot) {
      float* o = out + ((size_t)b * POST_NMS + j) * 5;
      o[0] = 0.f; o[1] = 0.f; o[2] = 0.f; o[3] = 0.f; o[4] = 0.f;
    }
  }
}

extern "C" void kernel_launch(void* const* d_in, const int* in_sizes, int n_in,
                              void* d_out, int out_size, void* d_ws, size_t ws_size,
                              hipStream_t stream) {
  const float* scores  = (const float*)d_in[0];
  const float* deltas  = (const float*)d_in[1];
  const float* anchors = (const float*)d_in[2];
  int A = in_sizes[2] / 4;          // 159882
  int B = in_sizes[0] / A;          // 16

  char* ws = (char*)d_ws;
  size_t off = 0;
  auto alloc = [&](size_t bytes) {
    void* p = ws + off;
    off += (bytes + 255) & ~(size_t)255;
    return p;
  };
  unsigned* ghist    = (unsigned*)alloc((size_t)B * NSLICE * NBINS * 4);
  int*      cand_cnt = (int*)alloc((size_t)B * 4);
  int*      T1       = (int*)alloc((size_t)B * 4);
  u64*      cand     = (u64*)alloc((size_t)B * CAP * 8);
  u64*      gsel     = (u64*)alloc((size_t)B * SORTN * 8);
  int*      sel_cnt  = (int*)alloc((size_t)B * 4);
  float*    topk_lg  = (float*)alloc((size_t)B * PRE_NMS * 4);
  float*    boxes    = (float*)alloc((size_t)B * PRE_NMS * 16);
  u64*      maskT    = (u64*)alloc((size_t)B * NWORDS * MROWS * 8);
  unsigned* gwf      = (unsigned*)alloc((size_t)B * NWORDS * 4);

  hist_kernel<<<dim3(B, NSLICE), 256, 0, stream>>>(scores, A, ghist, cand_cnt, gwf);
  compact_kernel<<<dim3(B, NSLICE), 256, 0, stream>>>(scores, A, ghist, cand, cand_cnt, T1);
  refine_select_kernel<<<B, 1024, 0, stream>>>(cand, cand_cnt, T1, gsel, sel_cnt);
  rank_decode_kernel<<<dim3(B, SORTN / 128), 256, 0, stream>>>(
      gsel, sel_cnt, deltas, anchors, A, boxes, topk_lg);
  iou_tile<<<dim3(NTILES, B), 64, 0, stream>>>(boxes, maskT, gwf);
  nms_scan<<<B, 256, 0, stream>>>(maskT, gwf, boxes, topk_lg, (float*)d_out);
}